// Round 10
// baseline (44.649 us; speedup 1.0000x reference)
//
#include <hip/hip_runtime.h>
#include <math.h>

#define RES 96
#define NV 97
#define NV2 (NV * NV)                      // 9409
#define NCELLS (RES * RES * RES)           // 884736
#define NBLK 6912                          // 24*24*12 tiles of 4x4x8
#define MAX_DISP (2.0f / 96.0f / 4.0f)
#define NVT 225                            // 5*5*9 tile vertices

typedef float f32x4 __attribute__((ext_vector_type(4)));

__device__ __forceinline__ float grid_coord(int a) {
    // linspace(-0.5,0.5,97)[a] * 2  ==  a/48 - 1
    return fmaf((float)a, 1.0f / 48.0f, -1.0f);
}

__device__ __forceinline__ float fast_tanh(float x) {
    x = fminf(fmaxf(x, -15.f), 15.f);
    const float e = __expf(2.f * x);
    return (e - 1.f) * __builtin_amdgcn_rcpf(e + 1.f);
}

// One block = 4x4x8 cell tile, 128 threads. Small LDS (14.4KB) -> ~8-10
// resident blocks/CU (vs 3.6 at the 256-thread/28.6KB tile) to hide the
// staging latency chains behind each barrier. Staging is phase-separated:
// all global loads issued to registers before any dependent compute/LDS
// traffic. Partials to DISTINCT addresses + tiny reduce kernel (same-address
// atomic tails serialize at the coherence point: 4x regression in R6/R7).
__global__ __launch_bounds__(128) void flexi_fused(
    const float* __restrict__ sdf,
    const float* __restrict__ deform,
    const float* __restrict__ weights,
    float* __restrict__ out_vd,
    float* __restrict__ partial)
{
    __shared__ float  wlds[16 * 168];      // 16 k-runs x 8 cells x 21 w = 10752B
    __shared__ float4 vs4[NVT];            // (x,y,z,sdf) per tile vertex, 3600B
    __shared__ float  sm[4];

    const int t = threadIdx.x;
    // chunked XCD swizzle (bijective: 6912 = 8*864)
    const int bidx = (blockIdx.x & 7) * 864 + (blockIdx.x >> 3);
    const int bi = bidx / 288;             // i-tile (0..23)
    const int rb = bidx - bi * 288;
    const int bj = rb / 12;                // j-tile (0..23)
    const int bk = rb - bj * 12;           // k-tile (0..11)

    // ---- phase 1: issue ALL weight loads into registers (in flight) ----
    // 16 segments x 42 float4 (one 8-cell k-run each, contiguous, 16B-aligned)
    const f32x4* w4 = reinterpret_cast<const f32x4*>(weights);
    f32x4 wreg[6];
    #pragma unroll
    for (int it = 0; it < 6; ++it) {
        const int u = t + it * 128;
        if (u < 672) {
            const int s = u / 42;
            const int q = u - s * 42;
            const int cs = (4 * bi + (s >> 2)) * 9216 + (4 * bj + (s & 3)) * 96 + 8 * bk;
            wreg[it] = __builtin_nontemporal_load(&w4[(size_t)(cs >> 2) * 21 + q]);  // cs%4==0
        }
    }

    // ---- phase 2: vertex gathers + tanh -> vs4 ----
    #pragma unroll
    for (int iv = 0; iv < 2; ++iv) {
        const int u = t + iv * 128;
        if (u < NVT) {
            const int a  = u / 45;             // 0..4
            const int r  = u - a * 45;
            const int b  = r / 9;              // 0..4
            const int cc = r - b * 9;          // 0..8
            const int gv = (4 * bi + a) * NV2 + (4 * bj + b) * NV + 8 * bk + cc;
            const float* dp = deform + (size_t)gv * 3;
            float4 vv;
            vv.x = grid_coord(4 * bi + a)  + MAX_DISP * fast_tanh(dp[0]);
            vv.y = grid_coord(4 * bj + b)  + MAX_DISP * fast_tanh(dp[1]);
            vv.z = grid_coord(8 * bk + cc) + MAX_DISP * fast_tanh(dp[2]);
            vv.w = sdf[gv];
            vs4[u] = vv;
        }
    }

    // ---- phase 3: dump weight regs to LDS (float4-index == u) ----
    #pragma unroll
    for (int it = 0; it < 6; ++it) {
        const int u = t + it * 128;
        if (u < 672) reinterpret_cast<f32x4*>(wlds)[u] = wreg[it];
    }
    __syncthreads();

    // ---- per-cell compute: t = ti*32 + tj*8 + tk ----
    const int ti = t >> 5;
    const int tj = (t >> 3) & 3;
    const int tk = t & 7;
    const int vbase = ti * 45 + tj * 9 + tk;
    const int OFF[8] = {0, 45, 9, 54, 1, 46, 10, 55};   // reference corner order

    float s[8], x[8][3];
    #pragma unroll
    for (int k = 0; k < 8; ++k) {
        const float4 vv = vs4[vbase + OFF[k]];
        x[k][0] = vv.x; x[k][1] = vv.y; x[k][2] = vv.z;
        s[k] = vv.w;
    }

    const float* wrow = &wlds[t * 21];     // == seg(t>>3)*168 + (t&7)*21
    float beta[12], alpha[8];
    #pragma unroll
    for (int e = 0; e < 12; ++e) beta[e] = wrow[e];
    #pragma unroll
    for (int k = 0; k < 8; ++k) alpha[k] = wrow[12 + k];
    const float gamma = wrow[20];

    const int EA[12] = {0, 1, 4, 0, 2, 3, 6, 2, 2, 3, 7, 6};
    const int EB[12] = {1, 5, 5, 4, 3, 7, 7, 6, 0, 1, 5, 4};

    float p[12][3];
    bool  cross[12];
    float wsum = 0.f, vnum0 = 0.f, vnum1 = 0.f, vnum2 = 0.f;
    int   ncross = 0;
    #pragma unroll
    for (int e = 0; e < 12; ++e) {
        const int a = EA[e], b = EB[e];
        const float sa = s[a], sb = s[b];
        const bool cr = (sa > 0.f) != (sb > 0.f);
        cross[e] = cr;
        const float ta = alpha[a] * sb;
        const float tb = alpha[b] * sa;
        // den guard keeps p finite (w=0 masks its value, but 0*inf = NaN)
        const float den = cr ? (ta - tb) : 1.0f;
        const float inv = __builtin_amdgcn_rcpf(den);
        const float p0 = (ta * x[a][0] - tb * x[b][0]) * inv;
        const float p1 = (ta * x[a][1] - tb * x[b][1]) * inv;
        const float p2 = (ta * x[a][2] - tb * x[b][2]) * inv;
        p[e][0] = p0; p[e][1] = p1; p[e][2] = p2;
        const float w = cr ? beta[e] : 0.f;
        wsum  += w;
        vnum0 += w * p0;
        vnum1 += w * p1;
        vnum2 += w * p2;
        ncross += cr ? 1 : 0;
    }

    const bool surf = (ncross > 0);
    const float invden = __builtin_amdgcn_rcpf(surf ? wsum : 1.0f);
    float vd0 = vnum0 * invden;
    float vd1 = vnum1 * invden;
    float vd2 = vnum2 * invden;
    if (!surf) { vd0 = 0.f; vd1 = 0.f; vd2 = 0.f; }

    const int c = (4 * bi + ti) * 9216 + (4 * bj + tj) * 96 + 8 * bk + tk;
    out_vd[(size_t)c * 3 + 0] = vd0;
    out_vd[(size_t)c * 3 + 1] = vd1;
    out_vd[(size_t)c * 3 + 2] = vd2;

    float devsum = 0.f;
    #pragma unroll
    for (int e = 0; e < 12; ++e) {
        const float d0 = p[e][0] - vd0;
        const float d1 = p[e][1] - vd1;
        const float d2 = p[e][2] - vd2;
        const float nrm = __builtin_amdgcn_sqrtf(d0 * d0 + d1 * d1 + d2 * d2 + 1e-12f);
        devsum += cross[e] ? nrm : 0.f;
    }
    const float dev = devsum * __builtin_amdgcn_rcpf(fmaxf((float)ncross, 1.0f));
    float regc = surf ? dev * gamma : 0.f;
    float cnt  = surf ? 1.0f : 0.f;

    #pragma unroll
    for (int off = 32; off > 0; off >>= 1) {
        regc += __shfl_down(regc, off);
        cnt  += __shfl_down(cnt, off);
    }
    const int wid = t >> 6;                // 2 waves per block
    if ((t & 63) == 0) { sm[wid] = regc; sm[2 + wid] = cnt; }
    __syncthreads();
    if (t == 0) {
        partial[bidx]        = sm[0] + sm[1];
        partial[NBLK + bidx] = sm[2] + sm[3];
    }
}

__global__ __launch_bounds__(256) void flexi_reduce(
    const float* __restrict__ partial, float* __restrict__ reg_out)
{
    float a = 0.f, b = 0.f;
    for (int i = threadIdx.x; i < NBLK; i += 256) {
        a += partial[i];
        b += partial[NBLK + i];
    }
    #pragma unroll
    for (int off = 32; off > 0; off >>= 1) {
        a += __shfl_down(a, off);
        b += __shfl_down(b, off);
    }
    __shared__ float sm[8];
    const int wid = threadIdx.x >> 6;
    if ((threadIdx.x & 63) == 0) { sm[wid] = a; sm[4 + wid] = b; }
    __syncthreads();
    if (threadIdx.x == 0) {
        const float num = sm[0] + sm[1] + sm[2] + sm[3];
        const float den = sm[4] + sm[5] + sm[6] + sm[7];
        reg_out[0] = num / fmaxf(den, 1.0f);
    }
}

extern "C" void kernel_launch(void* const* d_in, const int* in_sizes, int n_in,
                              void* d_out, int out_size, void* d_ws, size_t ws_size,
                              hipStream_t stream)
{
    // inputs: verts(analytic), indices(analytic), sdf, deform, weights
    const float* sdf     = (const float*)d_in[2];
    const float* deform  = (const float*)d_in[3];
    const float* weights = (const float*)d_in[4];
    float* out     = (float*)d_out;
    float* partial = (float*)d_ws;     // 2*NBLK floats, all rewritten each call

    flexi_fused<<<NBLK, 128, 0, stream>>>(sdf, deform, weights, out, partial);
    flexi_reduce<<<1, 256, 0, stream>>>(partial, out + (size_t)NCELLS * 3);
}